// Round 6
// baseline (2706.226 us; speedup 1.0000x reference)
//
#include <hip/hip_runtime.h>

#define T_LEN 2048
#define HID   256
#define G4    1024
#define EMBD  128
#define VOCAB 128
#define OUTC  2
#define BROW  4           // batch rows per WG = 2 chains x 2 rows
#define NWG   32
#define CHK   64          // x chunk staged in LDS
#define HSB   288         // habuf row stride BYTES (i8)
#define LOG2E 1.44269504088896340736f

typedef int i32x4 __attribute__((ext_vector_type(4)));

// Device-global scratch rebuilt every launch (kernel-boundary coherence, no fences).
__device__ float Pbuf[VOCAB * G4];                    // x-proj LUT, pre-scaled by -log2e / -2log2e
__device__ __align__(16) signed char Wqb[G4 * HID];   // int8 W_hh, row-major [gatecol][k]
__device__ float Winv[G4];                            // m/(127^2) * per-gate exp2 scale

__global__ void build_P(const float* __restrict__ emb, const float* __restrict__ W_ih,
                        const float* __restrict__ b_ih, const float* __restrict__ b_hh) {
    const int v = blockIdx.x >> 2;
    const int c = ((blockIdx.x & 3) << 8) + threadIdx.x;
    __shared__ float es[EMBD];
    if (threadIdx.x < EMBD) es[threadIdx.x] = emb[v * EMBD + threadIdx.x];
    __syncthreads();
    const float* wr = W_ih + c * EMBD;
    float acc = 0.f;
    #pragma unroll 8
    for (int e = 0; e < EMBD; ++e) acc += es[e] * wr[e];
    const float ks = ((c >> 8) == 2) ? (-2.f * LOG2E) : (-LOG2E);
    Pbuf[v * G4 + c] = (acc + b_ih[c] + b_hh[c]) * ks;
}

// per-row symmetric int8 quantization of W_hh (1024 rows x 256)
__global__ void quant_W(const float* __restrict__ W_hh) {
    const int row = blockIdx.x;
    const int k   = threadIdx.x;
    __shared__ float red[4];
    const float wv = W_hh[row * HID + k];
    float a = fabsf(wv);
    #pragma unroll
    for (int o = 32; o > 0; o >>= 1) a = fmaxf(a, __shfl_down(a, o, 64));
    if ((k & 63) == 0) red[k >> 6] = a;
    __syncthreads();
    const float m = fmaxf(fmaxf(fmaxf(red[0], red[1]), red[2]), fmaxf(red[3], 1e-30f));
    Wqb[row * HID + k] = (signed char)(int)rintf(wv * (127.f / m));
    const float ks = ((row >> 8) == 2) ? (-2.f * LOG2E) : (-LOG2E);
    if (k == 0) Winv[row] = m * (1.f / (127.f * 127.f)) * ks;
}

// r = 1/(1+2^p).  p = -x*log2e -> sigmoid(x); tanh(x) = 2*r(-2x*log2e)-1.
__device__ __forceinline__ float sig_p(float p) {
    return __builtin_amdgcn_rcpf(1.f + __builtin_amdgcn_exp2f(p));
}

// 32 WGs x 512 thr: one WG = TWO chains (A: rows 0-1, B: rows 2-3) sharing the
// register-resident int8 W_hh. Per step: MFMA_A, then MFMA_B interleaved with
// gate-math_A so VALU issues fill the MFMA pipe's shadow (breaks phase-lock).
__global__ __launch_bounds__(512, 2) void lstm_chain(
        const int* __restrict__ x, const float* __restrict__ fc_W,
        const float* __restrict__ fc_b, float* __restrict__ out) {
    __shared__ __align__(16) signed char habuf[2][2][2 * HSB]; // [ping][chain][row]
    __shared__ int   xch[BROW * CHK];
    __shared__ float hfin[BROW * HID];

    const int tid  = threadIdx.x;
    const int w    = tid >> 6;       // wave 0..7: gate-cols [32w, 32w+32), all 4 gates
    const int lane = tid & 63;
    const int l15  = lane & 15;
    const int quad = lane >> 4;
    const int bbase = blockIdx.x * BROW;
    const int ub    = w * 32;
    const int bq    = quad & 1;             // batch row within chain
    const int ntq   = quad >> 1;            // which acc tile holds this lane's cell
    const int colq  = ub + ntq * 16 + l15;  // this lane's gate-col
    const int arow  = (l15 >> 2) & 1;       // A-frag source row (8x M-replication)

    // persistent int8 B fragments: 2 tiles x 4 gates x 4 K-chunks x 4 regs = 128 regs
    i32x4 Bf[2][4][4];
    #pragma unroll
    for (int nt = 0; nt < 2; ++nt)
        #pragma unroll
        for (int g = 0; g < 4; ++g) {
            const signed char* wr = Wqb + (size_t)(g * HID + ub + nt * 16 + l15) * HID;
            #pragma unroll
            for (int kt = 0; kt < 4; ++kt)
                Bf[nt][g][kt] = *(const i32x4*)(wr + kt * 64 + quad * 16);
        }
    float winvv[4];                         // shared by both chains (same col per lane)
    #pragma unroll
    for (int g = 0; g < 4; ++g) winvv[g] = Winv[g * HID + colq];

    for (int i = tid; i < 2 * 2 * HSB; i += 512) ((signed char*)habuf[0])[i] = 0; // h_0=0

    float cst[2] = {0.f, 0.f};              // cell state per chain
    float xg[2][4];                         // pre-scaled xg per chain
    const i32x4 zero4 = {0, 0, 0, 0};

#define GATHER(TT)                                                            \
    {                                                                         \
        _Pragma("unroll")                                                     \
        for (int c = 0; c < 2; ++c) {                                         \
            const int xv = xch[(c * 2 + bq) * CHK + (TT)];                    \
            const float* pb = Pbuf + (size_t)xv * G4 + colq;                  \
            _Pragma("unroll")                                                 \
            for (int g = 0; g < 4; ++g) xg[c][g] = pb[g * HID];               \
        }                                                                     \
    }

#define MFMA8(ACC, AF, CSRC)                                                  \
    _Pragma("unroll")                                                         \
    for (int nt = 0; nt < 2; ++nt)                                            \
        _Pragma("unroll")                                                     \
        for (int g = 0; g < 4; ++g)                                           \
            ACC[nt][g] = __builtin_amdgcn_mfma_i32_16x16x64_i8(               \
                (AF), Bf[nt][g][_kt], CSRC, 0, 0, 0);

#define STEP(T, P, PN)                                                        \
    {                                                                         \
        const int t  = (T);                                                   \
        const int tt = t & (CHK - 1);                                         \
        if (tt == 0) {                                                        \
            if (tid < BROW * CHK)                                             \
                xch[tid] = x[(bbase + (tid >> 6)) * T_LEN + t + (tid & 63)];  \
            __syncthreads();                                                  \
            GATHER(0);                                                        \
        }                                                                     \
        i32x4 afA[4], afB[4];                                                 \
        _Pragma("unroll")                                                     \
        for (int kt = 0; kt < 4; ++kt) {                                      \
            afA[kt] = *(const i32x4*)(habuf[P][0] + arow * HSB + kt * 64 + quad * 16); \
            afB[kt] = *(const i32x4*)(habuf[P][1] + arow * HSB + kt * 64 + quad * 16); \
        }                                                                     \
        i32x4 accA[2][4], accB[2][4];                                         \
        { const int _kt = 0; MFMA8(accA, afA[0], zero4) }                     \
        { const int _kt = 1; MFMA8(accA, afA[1], accA[nt][g]) }               \
        { const int _kt = 2; MFMA8(accA, afA[2], accA[nt][g]) }               \
        { const int _kt = 3; MFMA8(accA, afA[3], accA[nt][g]) }               \
        { const int _kt = 0; MFMA8(accB, afB[0], zero4) }                     \
        { const int _kt = 1; MFMA8(accB, afB[1], accB[nt][g]) }               \
        /* gate_A preacts+sigmoids overlap MFMA_B */                          \
        const int aA0 = ntq ? accA[1][0][0] : accA[0][0][0];                  \
        const int aA1 = ntq ? accA[1][1][0] : accA[0][1][0];                  \
        const int aA2 = ntq ? accA[1][2][0] : accA[0][2][0];                  \
        const int aA3 = ntq ? accA[1][3][0] : accA[0][3][0];                  \
        const float isA = sig_p(fmaf((float)aA0, winvv[0], xg[0][0]));        \
        const float fsA = sig_p(fmaf((float)aA1, winvv[1], xg[0][1]));        \
        const float gtA = fmaf(2.f, sig_p(fmaf((float)aA2, winvv[2], xg[0][2])), -1.f); \
        const float osA = sig_p(fmaf((float)aA3, winvv[3], xg[0][3]));        \
        { const int _kt = 2; MFMA8(accB, afB[2], accB[nt][g]) }               \
        { const int _kt = 3; MFMA8(accB, afB[3], accB[nt][g]) }               \
        /* gate_A finish */                                                   \
        {                                                                     \
            const float c = fmaf(fsA, cst[0], isA * gtA);                     \
            cst[0] = c;                                                       \
            const float hq = fmaf(254.f, sig_p(c * (-2.f * LOG2E)), -127.f) * osA; \
            habuf[PN][0][bq * HSB + colq] = (signed char)(int)rintf(hq);      \
            if (t == T_LEN - 1) hfin[bq * HID + colq] = hq * (1.f / 127.f);   \
        }                                                                     \
        /* gate_B (MFMA pipe drains underneath) */                            \
        {                                                                     \
            const int aB0 = ntq ? accB[1][0][0] : accB[0][0][0];              \
            const int aB1 = ntq ? accB[1][1][0] : accB[0][1][0];              \
            const int aB2 = ntq ? accB[1][2][0] : accB[0][2][0];              \
            const int aB3 = ntq ? accB[1][3][0] : accB[0][3][0];              \
            const float isB = sig_p(fmaf((float)aB0, winvv[0], xg[1][0]));    \
            const float fsB = sig_p(fmaf((float)aB1, winvv[1], xg[1][1]));    \
            const float gtB = fmaf(2.f, sig_p(fmaf((float)aB2, winvv[2], xg[1][2])), -1.f); \
            const float osB = sig_p(fmaf((float)aB3, winvv[3], xg[1][3]));    \
            const float c = fmaf(fsB, cst[1], isB * gtB);                     \
            cst[1] = c;                                                       \
            const float hq = fmaf(254.f, sig_p(c * (-2.f * LOG2E)), -127.f) * osB; \
            habuf[PN][1][bq * HSB + colq] = (signed char)(int)rintf(hq);      \
            if (t == T_LEN - 1) hfin[(2 + bq) * HID + colq] = hq * (1.f / 127.f); \
        }                                                                     \
        if (tt != CHK - 1) GATHER(tt + 1);                                    \
        __syncthreads();                                                      \
    }

    #pragma unroll 1
    for (int t2 = 0; t2 < T_LEN; t2 += 2) {
        STEP(t2,     0, 1);
        STEP(t2 + 1, 1, 0);
    }
#undef STEP
#undef MFMA8
#undef GATHER

    // FC epilogue: logits[b,o] = hT[b,:] . fc_W[o,:] + fc_b[o]
    if (tid < BROW * OUTC) {
        const int b = tid >> 1, o = tid & 1;
        float s = fc_b[o];
        #pragma unroll 8
        for (int j = 0; j < HID; ++j) s += hfin[b * HID + j] * fc_W[o * HID + j];
        out[(bbase + b) * OUTC + o] = s;
    }
}

extern "C" void kernel_launch(void* const* d_in, const int* in_sizes, int n_in,
                              void* d_out, int out_size, void* d_ws, size_t ws_size,
                              hipStream_t stream) {
    const int*   x    = (const int*)  d_in[0];
    const float* emb  = (const float*)d_in[1];
    const float* W_ih = (const float*)d_in[2];
    const float* W_hh = (const float*)d_in[3];
    const float* b_ih = (const float*)d_in[4];
    const float* b_hh = (const float*)d_in[5];
    const float* fc_W = (const float*)d_in[6];
    const float* fc_b = (const float*)d_in[7];
    float* out = (float*)d_out;
    (void)d_ws; (void)ws_size;

    build_P<<<dim3(VOCAB * 4), dim3(256), 0, stream>>>(emb, W_ih, b_ih, b_hh);
    quant_W<<<dim3(G4), dim3(HID), 0, stream>>>(W_hh);
    lstm_chain<<<dim3(NWG), dim3(512), 0, stream>>>(x, fc_W, fc_b, out);
}

// Round 7
// 1788.609 us; speedup vs baseline: 1.5130x; 1.5130x over previous
//
#include <hip/hip_runtime.h>

#define T_LEN 2048
#define HID   256
#define G4    1024
#define EMBD  128
#define VOCAB 128
#define OUTC  2
#define BSUB  4           // batch rows per chain
#define NCHAIN 32
#define CHK   64          // x chunk staged in LDS
#define HSB   288         // habuf row stride BYTES (i8): bank shift 8/row -> conflict-free
#define LOG2E 1.44269504088896340736f

typedef int i32x4 __attribute__((ext_vector_type(4)));

// Device-global scratch rebuilt every launch (kernel-boundary coherence, no fences).
__device__ float Pbuf[VOCAB * G4];                    // x-proj LUT, pre-scaled by -log2e / -2log2e
__device__ __align__(16) signed char Wqb[G4 * HID];   // int8 W_hh, row-major [gatecol][k]
__device__ float Winv[G4];                            // m/(127^2) * per-gate exp2 scale

__global__ void build_P(const float* __restrict__ emb, const float* __restrict__ W_ih,
                        const float* __restrict__ b_ih, const float* __restrict__ b_hh) {
    const int v = blockIdx.x >> 2;
    const int c = ((blockIdx.x & 3) << 8) + threadIdx.x;
    __shared__ float es[EMBD];
    if (threadIdx.x < EMBD) es[threadIdx.x] = emb[v * EMBD + threadIdx.x];
    __syncthreads();
    const float* wr = W_ih + c * EMBD;
    float acc = 0.f;
    #pragma unroll 8
    for (int e = 0; e < EMBD; ++e) acc += es[e] * wr[e];
    const float ks = ((c >> 8) == 2) ? (-2.f * LOG2E) : (-LOG2E);
    Pbuf[v * G4 + c] = (acc + b_ih[c] + b_hh[c]) * ks;
}

// per-row symmetric int8 quantization of W_hh (1024 rows x 256)
__global__ void quant_W(const float* __restrict__ W_hh) {
    const int row = blockIdx.x;
    const int k   = threadIdx.x;
    __shared__ float red[4];
    const float wv = W_hh[row * HID + k];
    float a = fabsf(wv);
    #pragma unroll
    for (int o = 32; o > 0; o >>= 1) a = fmaxf(a, __shfl_down(a, o, 64));
    if ((k & 63) == 0) red[k >> 6] = a;
    __syncthreads();
    const float m = fmaxf(fmaxf(fmaxf(red[0], red[1]), red[2]), fmaxf(red[3], 1e-30f));
    Wqb[row * HID + k] = (signed char)(int)rintf(wv * (127.f / m));
    const float ks = ((row >> 8) == 2) ? (-2.f * LOG2E) : (-LOG2E);
    if (k == 0) Winv[row] = m * (1.f / (127.f * 127.f)) * ks;
}

// r = 1/(1+2^p).  p = -x*log2e -> sigmoid(x); tanh(x) = 2*r(-2x*log2e)-1.
__device__ __forceinline__ float sig_p(float p) {
    return __builtin_amdgcn_rcpf(1.f + __builtin_amdgcn_exp2f(p));
}

// 32 WGs x 512 thr: one WG = one chain of 4 batch rows, whole T loop on one CU.
// int8 W_hh resident (128 regs/lane); h replicated 4x in MFMA M-dim so every lane
// owns exactly 2 cells. xg prefetch issued at the TOP of each step so the
// compiler's vmcnt(0) drain before s_barrier costs ~nothing.
__global__ __launch_bounds__(512, 2) void lstm_chain(
        const int* __restrict__ x, const float* __restrict__ fc_W,
        const float* __restrict__ fc_b, float* __restrict__ out) {
    __shared__ __align__(16) signed char habuf[2][BSUB * HSB];
    __shared__ int   xch[BSUB * CHK];
    __shared__ float hfin[BSUB * HID];

    const int tid  = threadIdx.x;
    const int w    = tid >> 6;       // wave 0..7: owns units [32w, 32w+32), all 4 gates
    const int lane = tid & 63;
    const int l15  = lane & 15;
    const int quad = lane >> 4;      // == this lane's batch row
    const int bbase = blockIdx.x * BSUB;
    const int ub    = w * 32;

    // persistent int8 B fragments: 2 tiles x 4 gates x 4 K-chunks x 4 regs = 128 regs
    i32x4 Bf[2][4][4];
    float winvv[2][4];
    #pragma unroll
    for (int nt = 0; nt < 2; ++nt) {
        #pragma unroll
        for (int g = 0; g < 4; ++g) {
            const int row = g * HID + ub + nt * 16 + l15;
            const signed char* wr = Wqb + (size_t)row * HID;
            winvv[nt][g] = Winv[row];
            #pragma unroll
            for (int kt = 0; kt < 4; ++kt)
                Bf[nt][g][kt] = *(const i32x4*)(wr + kt * 64 + quad * 16);
        }
    }

    for (int i = tid; i < BSUB * HSB; i += 512) habuf[0][i] = 0;   // h_0 = 0

    float cst[2] = {0.f, 0.f};       // cell state: nt=0 -> col ub+l15, nt=1 -> col ub+16+l15
    float xga[2][4], xgb[2][4];      // double-buffered pre-scaled xg [nt][gate]
    const i32x4 zero4 = {0, 0, 0, 0};

#define GATHER(TT, XG)                                                        \
    {                                                                         \
        const int xv = xch[quad * CHK + (TT)];                                \
        const float* pb = Pbuf + (size_t)xv * G4 + ub + l15;                  \
        _Pragma("unroll")                                                     \
        for (int nt = 0; nt < 2; ++nt)                                        \
            _Pragma("unroll")                                                 \
            for (int g = 0; g < 4; ++g)                                       \
                XG[nt][g] = pb[g * HID + nt * 16];                            \
    }

#define STEP(T, HB, HN, XGC, XGN)                                             \
    {                                                                         \
        const int t  = (T);                                                   \
        const int tt = t & (CHK - 1);                                         \
        if (tt == 0) {                                                        \
            for (int i = tid; i < BSUB * CHK; i += 512)                       \
                xch[i] = x[(bbase + (i >> 6)) * T_LEN + t + (i & (CHK - 1))]; \
            __syncthreads();                                                  \
            GATHER(0, XGC);                                                   \
        }                                                                     \
        i32x4 af[4];                                                          \
        _Pragma("unroll")                                                     \
        for (int kt = 0; kt < 4; ++kt)                                        \
            af[kt] = *(const i32x4*)((HB) + (l15 >> 2) * HSB + kt * 64 + quad * 16); \
        /* prefetch next step's xg EARLY: lands under the MFMA+gate phase */  \
        if (tt != CHK - 1) GATHER(tt + 1, XGN);                               \
        i32x4 acc[2][4];                                                      \
        _Pragma("unroll")                                                     \
        for (int nt = 0; nt < 2; ++nt)                                        \
            _Pragma("unroll")                                                 \
            for (int g = 0; g < 4; ++g)                                       \
                acc[nt][g] = __builtin_amdgcn_mfma_i32_16x16x64_i8(           \
                    af[0], Bf[nt][g][0], zero4, 0, 0, 0);                     \
        _Pragma("unroll")                                                     \
        for (int kt = 1; kt < 4; ++kt)                                        \
            _Pragma("unroll")                                                 \
            for (int nt = 0; nt < 2; ++nt)                                    \
                _Pragma("unroll")                                             \
                for (int g = 0; g < 4; ++g)                                   \
                    acc[nt][g] = __builtin_amdgcn_mfma_i32_16x16x64_i8(       \
                        af[kt], Bf[nt][g][kt], acc[nt][g], 0, 0, 0);          \
        _Pragma("unroll")                                                     \
        for (int nt = 0; nt < 2; ++nt) {                                      \
            const int col = ub + nt * 16 + l15;                               \
            const float pi = fmaf((float)acc[nt][0][0], winvv[nt][0], XGC[nt][0]); \
            const float pf = fmaf((float)acc[nt][1][0], winvv[nt][1], XGC[nt][1]); \
            const float pg = fmaf((float)acc[nt][2][0], winvv[nt][2], XGC[nt][2]); \
            const float po = fmaf((float)acc[nt][3][0], winvv[nt][3], XGC[nt][3]); \
            const float is = sig_p(pi);                                       \
            const float fs = sig_p(pf);                                       \
            const float gt = fmaf(2.f, sig_p(pg), -1.f);                      \
            const float os = sig_p(po);                                       \
            const float c  = fmaf(fs, cst[nt], is * gt);                      \
            cst[nt] = c;                                                      \
            const float r2    = sig_p(c * (-2.f * LOG2E));                    \
            const float th127 = fmaf(254.f, r2, -127.f);                      \
            const float hq    = th127 * os;                                   \
            (HN)[quad * HSB + col] = (signed char)(int)rintf(hq);             \
            if (t == T_LEN - 1)                                               \
                hfin[quad * HID + col] = hq * (1.f / 127.f);                  \
        }                                                                     \
        __syncthreads();                                                      \
    }

    #pragma unroll 1
    for (int t2 = 0; t2 < T_LEN; t2 += 2) {
        STEP(t2,     habuf[0], habuf[1], xga, xgb);
        STEP(t2 + 1, habuf[1], habuf[0], xgb, xga);
    }
#undef STEP
#undef GATHER

    // FC epilogue: logits[b,o] = hT[b,:] . fc_W[o,:] + fc_b[o]
    if (tid < BSUB * OUTC) {
        const int b = tid >> 1, o = tid & 1;
        float s = fc_b[o];
        #pragma unroll 8
        for (int j = 0; j < HID; ++j) s += hfin[b * HID + j] * fc_W[o * HID + j];
        out[(bbase + b) * OUTC + o] = s;
    }
}

extern "C" void kernel_launch(void* const* d_in, const int* in_sizes, int n_in,
                              void* d_out, int out_size, void* d_ws, size_t ws_size,
                              hipStream_t stream) {
    const int*   x    = (const int*)  d_in[0];
    const float* emb  = (const float*)d_in[1];
    const float* W_ih = (const float*)d_in[2];
    const float* W_hh = (const float*)d_in[3];
    const float* b_ih = (const float*)d_in[4];
    const float* b_hh = (const float*)d_in[5];
    const float* fc_W = (const float*)d_in[6];
    const float* fc_b = (const float*)d_in[7];
    float* out = (float*)d_out;
    (void)d_ws; (void)ws_size;

    build_P<<<dim3(VOCAB * 4), dim3(256), 0, stream>>>(emb, W_ih, b_ih, b_hh);
    quant_W<<<dim3(G4), dim3(HID), 0, stream>>>(W_hh);
    lstm_chain<<<dim3(NCHAIN), dim3(512), 0, stream>>>(x, fc_W, fc_b, out);
}

// Round 8
// 1662.718 us; speedup vs baseline: 1.6276x; 1.0757x over previous
//
#include <hip/hip_runtime.h>

#define T_LEN 2048
#define HID   256
#define G4    1024
#define EMBD  128
#define VOCAB 128
#define OUTC  2
#define BSUB  4           // batch rows per chain
#define NCHAIN 32
#define CHK   64          // x chunk staged in LDS
#define XCHS  72          // xch row stride (ints): quads land on distinct banks
#define HSB   288         // habuf row stride bytes: HSB/4=72 == 8 mod 16 -> perfect 2-way banks (free)
#define LOG2E 1.44269504088896340736f

typedef int   i32x4 __attribute__((ext_vector_type(4)));
typedef float f32x4 __attribute__((ext_vector_type(4)));

// Device-global scratch rebuilt every launch (kernel-boundary coherence, no fences).
// Pbuf swizzled: [v][w][l15][nt*4+g] -- each lane's 8 xg values are 32 contiguous bytes.
__device__ __align__(16) float Pbuf[VOCAB * G4];
__device__ __align__(16) signed char Wqb[G4 * HID];   // int8 W_hh, row-major [gatecol][k]
__device__ float Winv[G4];                            // m/(127^2) * per-gate exp2 scale

__global__ void build_P(const float* __restrict__ emb, const float* __restrict__ W_ih,
                        const float* __restrict__ b_ih, const float* __restrict__ b_hh) {
    const int v = blockIdx.x >> 2;
    const int c = ((blockIdx.x & 3) << 8) + threadIdx.x;   // gate-col 0..1023
    __shared__ float es[EMBD];
    if (threadIdx.x < EMBD) es[threadIdx.x] = emb[v * EMBD + threadIdx.x];
    __syncthreads();
    const float* wr = W_ih + c * EMBD;
    float acc = 0.f;
    #pragma unroll 8
    for (int e = 0; e < EMBD; ++e) acc += es[e] * wr[e];
    const float ks = ((c >> 8) == 2) ? (-2.f * LOG2E) : (-LOG2E);
    // swizzle: c = g*256 + w*32 + nt*16 + l15  ->  idx = v*1024 + w*128 + l15*8 + nt*4 + g
    const int g  = c >> 8;
    const int rr = c & 255;
    const int wi = rr >> 5;
    const int nt = (rr >> 4) & 1;
    const int l  = rr & 15;
    Pbuf[v * G4 + wi * 128 + l * 8 + nt * 4 + g] = (acc + b_ih[c] + b_hh[c]) * ks;
}

// per-row symmetric int8 quantization of W_hh (1024 rows x 256)
__global__ void quant_W(const float* __restrict__ W_hh) {
    const int row = blockIdx.x;
    const int k   = threadIdx.x;
    __shared__ float red[4];
    const float wv = W_hh[row * HID + k];
    float a = fabsf(wv);
    #pragma unroll
    for (int o = 32; o > 0; o >>= 1) a = fmaxf(a, __shfl_down(a, o, 64));
    if ((k & 63) == 0) red[k >> 6] = a;
    __syncthreads();
    const float m = fmaxf(fmaxf(fmaxf(red[0], red[1]), red[2]), fmaxf(red[3], 1e-30f));
    Wqb[row * HID + k] = (signed char)(int)rintf(wv * (127.f / m));
    const float ks = ((row >> 8) == 2) ? (-2.f * LOG2E) : (-LOG2E);
    if (k == 0) Winv[row] = m * (1.f / (127.f * 127.f)) * ks;
}

// r = 1/(1+2^p).  p = -x*log2e -> sigmoid(x); tanh(x) = 2*r(-2x*log2e)-1.
__device__ __forceinline__ float sig_p(float p) {
    return __builtin_amdgcn_rcpf(1.f + __builtin_amdgcn_exp2f(p));
}

// 32 WGs x 512 thr: one WG = one chain of 4 batch rows, whole T loop on one CU.
// int8 W_hh register-resident. Step order: MFMA(nt0) -> MFMA(nt1) -> gate(nt0)
// -> gate(nt1): the nt1 MFMAs drain in the matrix pipe underneath gate(nt0) VALU.
__global__ __launch_bounds__(512, 2) void lstm_chain(
        const int* __restrict__ x, const float* __restrict__ fc_W,
        const float* __restrict__ fc_b, float* __restrict__ out) {
    __shared__ __align__(16) signed char habuf[2][BSUB * HSB];
    __shared__ int   xch[BSUB * XCHS];
    __shared__ float hfin[BSUB * HID];

    const int tid  = threadIdx.x;
    const int w    = tid >> 6;       // wave 0..7: owns units [32w, 32w+32), all 4 gates
    const int lane = tid & 63;
    const int l15  = lane & 15;
    const int quad = lane >> 4;      // == this lane's batch row
    const int bbase = blockIdx.x * BSUB;
    const int ub    = w * 32;

    // persistent int8 B fragments: 2 tiles x 4 gates x 4 K-chunks x 4 regs = 128 regs
    i32x4 Bf[2][4][4];
    float winvv[2][4];
    #pragma unroll
    for (int nt = 0; nt < 2; ++nt) {
        #pragma unroll
        for (int g = 0; g < 4; ++g) {
            const int row = g * HID + ub + nt * 16 + l15;
            const signed char* wr = Wqb + (size_t)row * HID;
            winvv[nt][g] = Winv[row];
            #pragma unroll
            for (int kt = 0; kt < 4; ++kt)
                Bf[nt][g][kt] = *(const i32x4*)(wr + kt * 64 + quad * 16);
        }
    }

    if (tid < BSUB * HSB / 4) ((int*)habuf[0])[tid] = 0;   // h_0 = 0

    float cst[2] = {0.f, 0.f};
    f32x4 xga0, xga1, xgb0, xgb1;    // double-buffered xg: [nt0 g0..3], [nt1 g0..3]
    const i32x4 zero4 = {0, 0, 0, 0};
    const float* pbase = Pbuf + w * 128 + l15 * 8;
    const signed char* habA = habuf[0] + (l15 >> 2) * HSB + quad * 16;
    const signed char* habB = habuf[1] + (l15 >> 2) * HSB + quad * 16;

#define GATHER(TT, X0, X1)                                                    \
    {                                                                         \
        const int xv = xch[quad * XCHS + (TT)];                               \
        const f32x4* pb = (const f32x4*)(pbase + (size_t)xv * G4);            \
        X0 = pb[0];                                                           \
        X1 = pb[1];                                                           \
    }

#define GATE(NT, ACC, XG, HN, TCUR)                                           \
    {                                                                         \
        const int col = ub + NT * 16 + l15;                                   \
        const float pi = fmaf((float)ACC[0][0], winvv[NT][0], XG[0]);         \
        const float pf = fmaf((float)ACC[1][0], winvv[NT][1], XG[1]);         \
        const float pg = fmaf((float)ACC[2][0], winvv[NT][2], XG[2]);         \
        const float po = fmaf((float)ACC[3][0], winvv[NT][3], XG[3]);         \
        const float is = sig_p(pi);                                           \
        const float fs = sig_p(pf);                                           \
        const float gt = fmaf(2.f, sig_p(pg), -1.f);                          \
        const float os = sig_p(po);                                           \
        const float c  = fmaf(fs, cst[NT], is * gt);                          \
        cst[NT] = c;                                                          \
        const float hq = fmaf(254.f, sig_p(c * (-2.f * LOG2E)), -127.f) * os; \
        (HN)[quad * HSB + col] = (signed char)(int)rintf(hq);                 \
        if ((TCUR) == T_LEN - 1) hfin[quad * HID + col] = hq * (1.f / 127.f); \
    }

#define STEP(HAB, HN, XC0, XC1, XN0, XN1, PF, TT, TCUR)                       \
    {                                                                         \
        i32x4 af[4];                                                          \
        _Pragma("unroll")                                                     \
        for (int kt = 0; kt < 4; ++kt)                                        \
            af[kt] = *(const i32x4*)((HAB) + kt * 64);                        \
        if (PF) GATHER((TT), XN0, XN1);                                       \
        i32x4 a0[4], a1[4];                                                   \
        _Pragma("unroll")                                                     \
        for (int g = 0; g < 4; ++g)                                           \
            a0[g] = __builtin_amdgcn_mfma_i32_16x16x64_i8(af[0], Bf[0][g][0], zero4, 0, 0, 0); \
        _Pragma("unroll")                                                     \
        for (int kt = 1; kt < 4; ++kt)                                        \
            _Pragma("unroll")                                                 \
            for (int g = 0; g < 4; ++g)                                       \
                a0[g] = __builtin_amdgcn_mfma_i32_16x16x64_i8(af[kt], Bf[0][g][kt], a0[g], 0, 0, 0); \
        _Pragma("unroll")                                                     \
        for (int g = 0; g < 4; ++g)                                           \
            a1[g] = __builtin_amdgcn_mfma_i32_16x16x64_i8(af[0], Bf[1][g][0], zero4, 0, 0, 0); \
        _Pragma("unroll")                                                     \
        for (int kt = 1; kt < 4; ++kt)                                        \
            _Pragma("unroll")                                                 \
            for (int g = 0; g < 4; ++g)                                       \
                a1[g] = __builtin_amdgcn_mfma_i32_16x16x64_i8(af[kt], Bf[1][g][kt], a1[g], 0, 0, 0); \
        /* gate(nt0) VALU overlaps the nt1 MFMAs still in the matrix pipe */  \
        GATE(0, a0, XC0, HN, TCUR);                                           \
        GATE(1, a1, XC1, HN, TCUR);                                           \
        __syncthreads();                                                      \
    }

    #pragma unroll 1
    for (int ch = 0; ch < T_LEN / CHK; ++ch) {
        // refill x chunk (prev step's end-barrier protects old readers)
        if (tid < BSUB * CHK)
            xch[(tid >> 6) * XCHS + (tid & 63)] =
                x[(bbase + (tid >> 6)) * T_LEN + ch * CHK + (tid & 63)];
        __syncthreads();
        GATHER(0, xga0, xga1);
        const int tb = ch * CHK;
        #pragma unroll 1
        for (int tt = 0; tt < CHK; tt += 2) {
            STEP(habA, habuf[1], xga0, xga1, xgb0, xgb1, 1, tt + 1, tb + tt);
            STEP(habB, habuf[0], xgb0, xgb1, xga0, xga1, (tt < CHK - 2), tt + 2, tb + tt + 1);
        }
    }
#undef STEP
#undef GATE
#undef GATHER

    // FC epilogue: logits[b,o] = hT[b,:] . fc_W[o,:] + fc_b[o]
    if (tid < BSUB * OUTC) {
        const int b = tid >> 1, o = tid & 1;
        float s = fc_b[o];
        #pragma unroll 8
        for (int j = 0; j < HID; ++j) s += hfin[b * HID + j] * fc_W[o * HID + j];
        out[(bbase + b) * OUTC + o] = s;
    }
}

extern "C" void kernel_launch(void* const* d_in, const int* in_sizes, int n_in,
                              void* d_out, int out_size, void* d_ws, size_t ws_size,
                              hipStream_t stream) {
    const int*   x    = (const int*)  d_in[0];
    const float* emb  = (const float*)d_in[1];
    const float* W_ih = (const float*)d_in[2];
    const float* W_hh = (const float*)d_in[3];
    const float* b_ih = (const float*)d_in[4];
    const float* b_hh = (const float*)d_in[5];
    const float* fc_W = (const float*)d_in[6];
    const float* fc_b = (const float*)d_in[7];
    float* out = (float*)d_out;
    (void)d_ws; (void)ws_size;

    build_P<<<dim3(VOCAB * 4), dim3(256), 0, stream>>>(emb, W_ih, b_ih, b_hh);
    quant_W<<<dim3(G4), dim3(HID), 0, stream>>>(W_hh);
    lstm_chain<<<dim3(NCHAIN), dim3(512), 0, stream>>>(x, fc_W, fc_b, out);
}

// Round 9
// 1413.852 us; speedup vs baseline: 1.9141x; 1.1760x over previous
//
#include <hip/hip_runtime.h>

#define T_LEN 2048
#define HID   256
#define G4    1024
#define EMBD  128
#define VOCAB 128
#define OUTC  2
#define BSUB  2           // batch rows per chain
#define NWG   64
#define CHK   64          // x chunk staged in LDS
#define XCHS  72          // xch row stride (ints)
#define HSB   288         // habuf row stride bytes
#define LOG2E 1.44269504088896340736f

typedef int   i32x4 __attribute__((ext_vector_type(4)));
typedef float f32x4 __attribute__((ext_vector_type(4)));

// Device-global scratch rebuilt every launch (kernel-boundary coherence, no fences).
// Pbuf swizzled: [v][w][nt][l15][g] -- each lane's 4 xg values are 16 contiguous bytes.
__device__ __align__(16) float Pbuf[VOCAB * G4];
__device__ __align__(16) signed char Wqb[G4 * HID];   // int8 W_hh, row-major [gatecol][k]
__device__ float Winv[G4];                            // m/(127^2) * per-gate exp2 scale

__global__ void build_P(const float* __restrict__ emb, const float* __restrict__ W_ih,
                        const float* __restrict__ b_ih, const float* __restrict__ b_hh) {
    const int v = blockIdx.x >> 2;
    const int c = ((blockIdx.x & 3) << 8) + threadIdx.x;   // gate-col 0..1023
    __shared__ float es[EMBD];
    if (threadIdx.x < EMBD) es[threadIdx.x] = emb[v * EMBD + threadIdx.x];
    __syncthreads();
    const float* wr = W_ih + c * EMBD;
    float acc = 0.f;
    #pragma unroll 8
    for (int e = 0; e < EMBD; ++e) acc += es[e] * wr[e];
    const float ks = ((c >> 8) == 2) ? (-2.f * LOG2E) : (-LOG2E);
    // c = g*256 + w*32 + nt*16 + l15  ->  idx = v*1024 + w*128 + nt*64 + l15*4 + g
    const int g  = c >> 8;
    const int rr = c & 255;
    const int wi = rr >> 5;
    const int nt = (rr >> 4) & 1;
    const int l  = rr & 15;
    Pbuf[v * G4 + wi * 128 + nt * 64 + l * 4 + g] = (acc + b_ih[c] + b_hh[c]) * ks;
}

// per-row symmetric int8 quantization of W_hh (1024 rows x 256)
__global__ void quant_W(const float* __restrict__ W_hh) {
    const int row = blockIdx.x;
    const int k   = threadIdx.x;
    __shared__ float red[4];
    const float wv = W_hh[row * HID + k];
    float a = fabsf(wv);
    #pragma unroll
    for (int o = 32; o > 0; o >>= 1) a = fmaxf(a, __shfl_down(a, o, 64));
    if ((k & 63) == 0) red[k >> 6] = a;
    __syncthreads();
    const float m = fmaxf(fmaxf(fmaxf(red[0], red[1]), red[2]), fmaxf(red[3], 1e-30f));
    Wqb[row * HID + k] = (signed char)(int)rintf(wv * (127.f / m));
    const float ks = ((row >> 8) == 2) ? (-2.f * LOG2E) : (-LOG2E);
    if (k == 0) Winv[row] = m * (1.f / (127.f * 127.f)) * ks;
}

// r = 1/(1+2^p).  p = -x*log2e -> sigmoid(x); tanh(x) = 2*r(-2x*log2e)-1.
__device__ __forceinline__ float sig_p(float p) {
    return __builtin_amdgcn_rcpf(1.f + __builtin_amdgcn_exp2f(p));
}

// 64 WGs x 512 thr: one WG = one chain of 2 batch rows. Same per-CU matrix floor
// (256 mfma/step), but each lane owns exactly ONE gate-cell:
//   batch = quad>>1, nt = quad&1, col = ub + nt*16 + l15   (acc tile via cndmask)
// -> VALU tail halves vs the 32-WG config, 64 CUs active.
__global__ __launch_bounds__(512, 2) void lstm_chain(
        const int* __restrict__ x, const float* __restrict__ fc_W,
        const float* __restrict__ fc_b, float* __restrict__ out) {
    __shared__ __align__(16) signed char habuf[2][BSUB * HSB];
    __shared__ int   xch[BSUB * XCHS];
    __shared__ float hfin[BSUB * HID];

    const int tid  = threadIdx.x;
    const int w    = tid >> 6;       // wave 0..7: owns units [32w, 32w+32), all 4 gates
    const int lane = tid & 63;
    const int l15  = lane & 15;
    const int quad = lane >> 4;
    const int bbase = blockIdx.x * BSUB;
    const int ub    = w * 32;
    const int bq    = quad >> 1;              // this lane's batch row
    const int ntq   = quad & 1;               // this lane's acc tile
    const int colq  = ub + ntq * 16 + l15;    // this lane's gate-col (within gate block)

    // persistent int8 B fragments: 2 tiles x 4 gates x 4 K-chunks x 4 regs = 128 regs
    i32x4 Bf[2][4][4];
    #pragma unroll
    for (int nt = 0; nt < 2; ++nt)
        #pragma unroll
        for (int g = 0; g < 4; ++g) {
            const signed char* wr = Wqb + (size_t)(g * HID + ub + nt * 16 + l15) * HID;
            #pragma unroll
            for (int kt = 0; kt < 4; ++kt)
                Bf[nt][g][kt] = *(const i32x4*)(wr + kt * 64 + quad * 16);
        }
    float winvv[4];                           // per-gate dequant for THIS lane's col
    #pragma unroll
    for (int g = 0; g < 4; ++g) winvv[g] = Winv[g * HID + colq];

    if (tid < BSUB * HSB / 4) ((int*)habuf[0])[tid] = 0;   // h_0 = 0

    float cst = 0.f;                          // single cell state per lane
    f32x4 xga, xgb;                           // double-buffered xg (4 gates)
    const i32x4 zero4 = {0, 0, 0, 0};
    const float* pbase = Pbuf + w * 128 + ntq * 64 + l15 * 4;
    const signed char* habA = habuf[0] + (l15 >> 3) * HSB + quad * 16;
    const signed char* habB = habuf[1] + (l15 >> 3) * HSB + quad * 16;

#define GATHER(TT, XG)                                                        \
    {                                                                         \
        const int xv = xch[bq * XCHS + (TT)];                                 \
        XG = *(const f32x4*)(pbase + (size_t)xv * G4);                        \
    }

#define STEP(HAB, HN, XC, XN, PF, TT, TCUR)                                   \
    {                                                                         \
        i32x4 af[4];                                                          \
        _Pragma("unroll")                                                     \
        for (int kt = 0; kt < 4; ++kt)                                        \
            af[kt] = *(const i32x4*)((HAB) + kt * 64);                        \
        if (PF) GATHER((TT), XN);                                             \
        i32x4 a0[4], a1[4];                                                   \
        _Pragma("unroll")                                                     \
        for (int g = 0; g < 4; ++g)                                           \
            a0[g] = __builtin_amdgcn_mfma_i32_16x16x64_i8(af[0], Bf[0][g][0], zero4, 0, 0, 0); \
        _Pragma("unroll")                                                     \
        for (int kt = 1; kt < 4; ++kt)                                        \
            _Pragma("unroll")                                                 \
            for (int g = 0; g < 4; ++g)                                       \
                a0[g] = __builtin_amdgcn_mfma_i32_16x16x64_i8(af[kt], Bf[0][g][kt], a0[g], 0, 0, 0); \
        _Pragma("unroll")                                                     \
        for (int g = 0; g < 4; ++g)                                           \
            a1[g] = __builtin_amdgcn_mfma_i32_16x16x64_i8(af[0], Bf[1][g][0], zero4, 0, 0, 0); \
        _Pragma("unroll")                                                     \
        for (int kt = 1; kt < 4; ++kt)                                        \
            _Pragma("unroll")                                                 \
            for (int g = 0; g < 4; ++g)                                       \
                a1[g] = __builtin_amdgcn_mfma_i32_16x16x64_i8(af[kt], Bf[1][g][kt], a1[g], 0, 0, 0); \
        /* ONE gate-cell per lane: tile select via cndmask */                 \
        const int gi_ = ntq ? a1[0][0] : a0[0][0];                            \
        const int gf_ = ntq ? a1[1][0] : a0[1][0];                            \
        const int gg_ = ntq ? a1[2][0] : a0[2][0];                            \
        const int go_ = ntq ? a1[3][0] : a0[3][0];                            \
        const float is = sig_p(fmaf((float)gi_, winvv[0], XC[0]));            \
        const float fs = sig_p(fmaf((float)gf_, winvv[1], XC[1]));            \
        const float gt = fmaf(2.f, sig_p(fmaf((float)gg_, winvv[2], XC[2])), -1.f); \
        const float os = sig_p(fmaf((float)go_, winvv[3], XC[3]));            \
        const float c  = fmaf(fs, cst, is * gt);                              \
        cst = c;                                                              \
        const float hq = fmaf(254.f, sig_p(c * (-2.f * LOG2E)), -127.f) * os; \
        (HN)[bq * HSB + colq] = (signed char)(int)rintf(hq);                  \
        if ((TCUR) == T_LEN - 1) hfin[bq * HID + colq] = hq * (1.f / 127.f);  \
        __syncthreads();                                                      \
    }

    #pragma unroll 1
    for (int ch = 0; ch < T_LEN / CHK; ++ch) {
        // refill x chunk (prev step's end-barrier protects old readers)
        if (tid < BSUB * CHK)
            xch[(tid >> 6) * XCHS + (tid & 63)] =
                x[(bbase + (tid >> 6)) * T_LEN + ch * CHK + (tid & 63)];
        __syncthreads();
        GATHER(0, xga);
        const int tb = ch * CHK;
        #pragma unroll 1
        for (int tt = 0; tt < CHK; tt += 2) {
            STEP(habA, habuf[1], xga, xgb, 1, tt + 1, tb + tt);
            STEP(habB, habuf[0], xgb, xga, (tt < CHK - 2), tt + 2, tb + tt + 1);
        }
    }
#undef STEP
#undef GATHER

    // FC epilogue: logits[b,o] = hT[b,:] . fc_W[o,:] + fc_b[o]
    if (tid < BSUB * OUTC) {
        const int b = tid >> 1, o = tid & 1;
        float s = fc_b[o];
        #pragma unroll 8
        for (int j = 0; j < HID; ++j) s += hfin[b * HID + j] * fc_W[o * HID + j];
        out[(bbase + b) * OUTC + o] = s;
    }
}

extern "C" void kernel_launch(void* const* d_in, const int* in_sizes, int n_in,
                              void* d_out, int out_size, void* d_ws, size_t ws_size,
                              hipStream_t stream) {
    const int*   x    = (const int*)  d_in[0];
    const float* emb  = (const float*)d_in[1];
    const float* W_ih = (const float*)d_in[2];
    const float* W_hh = (const float*)d_in[3];
    const float* b_ih = (const float*)d_in[4];
    const float* b_hh = (const float*)d_in[5];
    const float* fc_W = (const float*)d_in[6];
    const float* fc_b = (const float*)d_in[7];
    float* out = (float*)d_out;
    (void)d_ws; (void)ws_size;

    build_P<<<dim3(VOCAB * 4), dim3(256), 0, stream>>>(emb, W_ih, b_ih, b_hh);
    quant_W<<<dim3(G4), dim3(HID), 0, stream>>>(W_hh);
    lstm_chain<<<dim3(NWG), dim3(512), 0, stream>>>(x, fc_W, fc_b, out);
}